// Round 1
// 7828.453 us; speedup vs baseline: 2.2779x; 2.2779x over previous
//
#include <hip/hip_runtime.h>
#include <hip/hip_bf16.h>
#include <math.h>

typedef __attribute__((ext_vector_type(8))) short short8;
typedef __attribute__((ext_vector_type(4))) float floatx4;

__device__ __forceinline__ float u2f(unsigned short u) {
    union { unsigned int i; float f; } x; x.i = ((unsigned int)u) << 16; return x.f;
}
__device__ __forceinline__ unsigned short f2u(float f) {
    union { float f; unsigned int i; } c; c.f = f;
    unsigned int r = c.i + 0x7FFF + ((c.i >> 16) & 1);   // round-to-nearest-even
    return (unsigned short)(r >> 16);
}
__device__ __forceinline__ float gelu_exact(float x) {
    return 0.5f * x * (1.0f + erff(x * 0.7071067811865475f));
}

// ===================== Kernel P: pack weights to bf16, k-contiguous ========
// W1t[n][k] = bf16(W1[k][n])  (1024 x 256)
// W2t[n][k] = bf16(W2[k][n])  ( 256 x 1024)
__global__ __launch_bounds__(256) void pack_weights_k(
    const float* __restrict__ W1, const float* __restrict__ W2,
    unsigned short* __restrict__ W1t, unsigned short* __restrict__ W2t)
{
    int b = blockIdx.x, t = threadIdx.x;
    if (b < 1024) {
        W1t[(size_t)b * 256 + t] = f2u(W1[(size_t)t * 1024 + b]);
    } else {
        int n = b - 1024;
        for (int it = 0; it < 4; ++it) {
            int k = it * 256 + t;
            W2t[(size_t)n * 1024 + k] = f2u(W2[(size_t)k * 256 + n]);
        }
    }
}

// ===================== Kernel A: LN1 + window attention + proj residual =====
// One block per window w = bt*32 + p (1024 blocks, 256 threads).
__global__ __launch_bounds__(256) void attn_block_k(
    const float* __restrict__ x, const float* __restrict__ mask,
    const float* __restrict__ adj,
    const float* __restrict__ g1, const float* __restrict__ be1,
    const float* __restrict__ Wqkv, const float* __restrict__ Bqkv,
    const float* __restrict__ Wp, const float* __restrict__ Bp,
    float* __restrict__ out)
{
    __shared__ unsigned short y[64][256];            // LN output, bf16 bits
    __shared__ unsigned short q[64][34], kk[64][34], v[64][34];
    __shared__ float s[64][65];
    int w = blockIdx.x, p = w & 31, t = threadIdx.x;
    int wave = t >> 6, lane = t & 63;
    size_t base = (size_t)w * 16384;                 // w*64*256

    // ---- LN over D=256 per row; also out = x (fp32 residual init) ----
    for (int it = 0; it < 16; ++it) {
        int r = it * 4 + wave;
        float vals[4]; float sum = 0.f, sq = 0.f;
#pragma unroll
        for (int k2 = 0; k2 < 4; ++k2) {
            float vv = x[base + (size_t)r * 256 + lane + 64 * k2];
            vals[k2] = vv; sum += vv; sq += vv * vv;
        }
        for (int o = 32; o > 0; o >>= 1) { sum += __shfl_xor(sum, o); sq += __shfl_xor(sq, o); }
        float mu = sum * (1.f / 256.f);
        float var = sq * (1.f / 256.f) - mu * mu;
        float rstd = rsqrtf(var + 1e-5f);
#pragma unroll
        for (int k2 = 0; k2 < 4; ++k2) {
            int c = lane + 64 * k2;
            y[r][c] = f2u((vals[k2] - mu) * rstd * g1[c] + be1[c]);
            out[base + (size_t)r * 256 + c] = vals[k2];
        }
    }
    __syncthreads();

    int n = t >> 2, c0 = (t & 3) * 64;   // epilogue/proj ownership: row n, 64 cols
    float oacc[64];
#pragma unroll
    for (int cc = 0; cc < 64; ++cc) oacc[cc] = Bp[c0 + cc];

    for (int h = 0; h < 8; ++h) {
        // ---- qkv for head h: 64 x (3x32) outputs ----
        for (int j = 0; j < 24; ++j) {
            int oi = j * 256 + t;
            int nn = oi / 96, c96 = oi % 96;
            int which = c96 >> 5, d = c96 & 31;
            int gcol = which * 256 + h * 32 + d;     // qkv col layout: s*256 + h*32 + d
            float acc = Bqkv[gcol];
            for (int dd = 0; dd < 256; ++dd)
                acc += u2f(y[nn][dd]) * Wqkv[(size_t)dd * 768 + gcol];
            unsigned short ub = f2u(acc);
            if (which == 0) q[nn][d] = ub;
            else if (which == 1) kk[nn][d] = ub;
            else v[nn][d] = ub;
        }
        __syncthreads();
        // ---- scores s[i][j] = q.k * hd^-0.5 + log(adj+1e-6) ----
        for (int j = 0; j < 16; ++j) {
            int idx = j * 256 + t;
            int i = idx >> 6, jj = idx & 63;
            float a = 0.f;
#pragma unroll
            for (int d = 0; d < 32; ++d) a += u2f(q[i][d]) * u2f(kk[jj][d]);
            s[i][jj] = a * 0.17677669529663689f + logf(adj[i * 64 + jj] + 1e-6f);
        }
        __syncthreads();
        // ---- softmax, 4 lanes per row ----
        {
            int r = t >> 2, sub = t & 3;
            float mx = -1e30f;
            for (int jj = sub; jj < 64; jj += 4) mx = fmaxf(mx, s[r][jj]);
            mx = fmaxf(mx, __shfl_xor(mx, 1)); mx = fmaxf(mx, __shfl_xor(mx, 2));
            float sum = 0.f;
            for (int jj = sub; jj < 64; jj += 4) { float e = __expf(s[r][jj] - mx); s[r][jj] = e; sum += e; }
            sum += __shfl_xor(sum, 1); sum += __shfl_xor(sum, 2);
            float inv = 1.f / sum;
            for (int jj = sub; jj < 64; jj += 4) s[r][jj] *= inv;
        }
        __syncthreads();
        // ---- o = softmax @ v, stored into q (q dead after scores) ----
        for (int j = 0; j < 8; ++j) {
            int idx = j * 256 + t;
            int i = idx >> 5, d = idx & 31;
            float a = 0.f;
            for (int jj = 0; jj < 64; ++jj) a += s[i][jj] * u2f(v[jj][d]);
            q[i][d] = f2u(a);
        }
        __syncthreads();
        // ---- proj accumulate: oacc += o_h @ Wp[h*32:(h+1)*32, :] ----
        for (int d = 0; d < 32; ++d) {
            float ov = u2f(q[n][d]);
            const float* wrow = Wp + (size_t)(h * 32 + d) * 256 + c0;
#pragma unroll
            for (int cc = 0; cc < 64; ++cc) oacc[cc] += ov * wrow[cc];
        }
        __syncthreads();
    }
    // ---- epilogue: out += oacc * mask[p][n]  (fp32 RMW) ----
    float mv = mask[p * 64 + n];
    for (int cc = 0; cc < 64; ++cc) {
        size_t idx = base + (size_t)n * 256 + c0 + cc;
        out[idx] += oacc[cc] * mv;
    }
}

// ===================== Kernel B: LN2 + MLP residual (MFMA) =================
// One block per window (1024 blocks, 256 threads = 4 waves).
// fc1: 16 passes x 64 cols, each wave a 16x64 strip (1 A + 4 B reads, 4 MFMA/kstep)
// fc2: persistent 64x64 per-wave tile (4x4 frags), accumulated over passes.
__global__ __launch_bounds__(256) void mlp_mfma_k(
    const float* __restrict__ mask,
    const float* __restrict__ g2, const float* __restrict__ be2,
    const unsigned short* __restrict__ W1t, const float* __restrict__ B1,
    const unsigned short* __restrict__ W2t, const float* __restrict__ B2,
    float* __restrict__ out)
{
    __shared__ unsigned short Ybuf[64][264];   // 33792 B, +8 pad -> 2-way-free b128 reads
    __shared__ unsigned short Hbuf[64][72];    //  9216 B, 64 k + 8 pad
    __shared__ unsigned short Wbuf[10240];     // 20480 B, rows of 40 shorts (32 k + 8 pad)
    int w = blockIdx.x, p = w & 31, t = threadIdx.x;
    int wave = t >> 6, lane = t & 63;
    int l15 = lane & 15, kw = lane >> 4;
    size_t base = (size_t)w * 16384;

    // ---- LN2 from out (= x5 after attention, fp32) -> bf16 Ybuf ----
    for (int it = 0; it < 16; ++it) {
        int r = it * 4 + wave;
        float vals[4]; float sum = 0.f, sq = 0.f;
#pragma unroll
        for (int k2 = 0; k2 < 4; ++k2) {
            float vv = out[base + (size_t)r * 256 + lane + 64 * k2];
            vals[k2] = vv; sum += vv; sq += vv * vv;
        }
        for (int o = 32; o > 0; o >>= 1) { sum += __shfl_xor(sum, o); sq += __shfl_xor(sq, o); }
        float mu = sum * (1.f / 256.f);
        float var = sq * (1.f / 256.f) - mu * mu;
        float rstd = rsqrtf(var + 1e-5f);
#pragma unroll
        for (int k2 = 0; k2 < 4; ++k2) {
            int c = lane + 64 * k2;
            Ybuf[r][c] = f2u((vals[k2] - mu) * rstd * g2[c] + be2[c]);
        }
    }
    __syncthreads();

    // persistent fc2 accumulator: wave owns all 64 rows x cols [wave*64, wave*64+64)
    floatx4 oacc[4][4];
#pragma unroll
    for (int m = 0; m < 4; ++m)
#pragma unroll
        for (int j = 0; j < 4; ++j) {
            float bb = B2[wave * 64 + j * 16 + l15];
            oacc[m][j] = (floatx4){bb, bb, bb, bb};
        }

    for (int pass = 0; pass < 16; ++pass) {
        // ---- fc1: H[:, pass*64 .. +64) = gelu(Y @ W1 + b1) ----
        floatx4 facc[4];
#pragma unroll
        for (int j = 0; j < 4; ++j) {
            float bb = B1[pass * 64 + j * 16 + l15];
            facc[j] = (floatx4){bb, bb, bb, bb};
        }
        {   // stage kstep 0 into half 0 (64 rows x 32 k = 256 x 16B chunks)
            int nr = t >> 2, c = t & 3;
            *(short8*)(Wbuf + nr * 40 + c * 8) =
                *(const short8*)(W1t + (size_t)(pass * 64 + nr) * 256 + c * 8);
        }
        __syncthreads();
        for (int ks = 0; ks < 8; ++ks) {
            if (ks + 1 < 8) {   // prefetch next k-slab into other half
                int nr = t >> 2, c = t & 3;
                *(short8*)(Wbuf + ((ks + 1) & 1) * 2560 + nr * 40 + c * 8) =
                    *(const short8*)(W1t + (size_t)(pass * 64 + nr) * 256 + (ks + 1) * 32 + c * 8);
            }
            int h = (ks & 1) * 2560;
            short8 a = *(const short8*)(&Ybuf[wave * 16 + l15][ks * 32 + kw * 8]);
            short8 bf[4];
#pragma unroll
            for (int j = 0; j < 4; ++j)
                bf[j] = *(const short8*)(Wbuf + h + (j * 16 + l15) * 40 + kw * 8);
#pragma unroll
            for (int j = 0; j < 4; ++j)
                facc[j] = __builtin_amdgcn_mfma_f32_16x16x32_bf16(a, bf[j], facc[j], 0, 0, 0);
            __syncthreads();
        }
        // gelu + write H tile (wave's 16 rows; C layout: row=kw*4+jj, col=j*16+l15)
#pragma unroll
        for (int j = 0; j < 4; ++j)
#pragma unroll
            for (int jj = 0; jj < 4; ++jj)
                Hbuf[wave * 16 + kw * 4 + jj][j * 16 + l15] = f2u(gelu_exact(facc[j][jj]));
        __syncthreads();

        // ---- fc2 partial: oacc += H_pass @ W2[pass*64 .. +64, :] ----
        for (int ks2 = 0; ks2 < 2; ++ks2) {
            for (int it = 0; it < 4; ++it) {   // stage 256 rows x 32 k (1024 chunks)
                int idx = it * 256 + t;
                int nr = idx >> 2, c = idx & 3;
                *(short8*)(Wbuf + nr * 40 + c * 8) =
                    *(const short8*)(W2t + (size_t)nr * 1024 + pass * 64 + ks2 * 32 + c * 8);
            }
            __syncthreads();
            short8 af[4], bf[4];
#pragma unroll
            for (int m = 0; m < 4; ++m)
                af[m] = *(const short8*)(&Hbuf[m * 16 + l15][ks2 * 32 + kw * 8]);
#pragma unroll
            for (int j = 0; j < 4; ++j)
                bf[j] = *(const short8*)(Wbuf + (wave * 64 + j * 16 + l15) * 40 + kw * 8);
#pragma unroll
            for (int m = 0; m < 4; ++m)
#pragma unroll
                for (int j = 0; j < 4; ++j)
                    oacc[m][j] = __builtin_amdgcn_mfma_f32_16x16x32_bf16(af[m], bf[j], oacc[m][j], 0, 0, 0);
            __syncthreads();
        }
    }

    // ---- epilogue: out += oacc * mask[p][row]  (fp32 RMW) ----
#pragma unroll
    for (int m = 0; m < 4; ++m) {
#pragma unroll
        for (int jj = 0; jj < 4; ++jj) {
            int r = m * 16 + kw * 4 + jj;
            float mv = mask[p * 64 + r];
#pragma unroll
            for (int j = 0; j < 4; ++j) {
                size_t idx = base + (size_t)r * 256 + wave * 64 + j * 16 + l15;
                out[idx] += oacc[m][j][jj] * mv;
            }
        }
    }
}

// ===================== Kernel C: pooled z-branch ============================
// One block per bt (32 blocks). Touches only its own bt's windows.
__global__ __launch_bounds__(256) void zbranch_k(
    const float* __restrict__ mask,
    const float* __restrict__ gb, const float* __restrict__ bb,
    const float* __restrict__ Wqkv, const float* __restrict__ Bqkv,
    const float* __restrict__ Wp, const float* __restrict__ Bp,
    const float* __restrict__ W1, const float* __restrict__ B1,
    const float* __restrict__ W2, const float* __restrict__ B2,
    float* __restrict__ out)
{
    __shared__ float zs[32][257];                 // pooled z -> LN'd z -> attn out
    __shared__ float q[32][33], kk[32][33], v[32][33];
    __shared__ float s[32][65];                   // scores; reused as fc1 htile
    int bt = blockIdx.x, t = threadIdx.x;
    int wave = t >> 6, lane = t & 63;
    size_t base = (size_t)bt * 524288;            // bt*32*64*256

    // ---- masked mean-pool over N=64 ----
    for (int j = 0; j < 32; ++j) {
        int oi = j * 256 + t;
        int p = oi >> 8, c = oi & 255;
        float msum = 0.f, acc = 0.f;
        for (int nn = 0; nn < 64; ++nn) {
            float mv = mask[p * 64 + nn];
            msum += mv;
            acc += mv * out[base + (size_t)(p * 64 + nn) * 256 + c];
        }
        zs[p][c] = acc / fmaxf(msum, 1.0f);
    }
    __syncthreads();
    // ---- LN over D=256, rows 32, in place ----
    for (int it = 0; it < 8; ++it) {
        int r = it * 4 + wave;
        float vals[4]; float sum = 0.f, sq = 0.f;
#pragma unroll
        for (int k2 = 0; k2 < 4; ++k2) {
            float vv = zs[r][lane + 64 * k2];
            vals[k2] = vv; sum += vv; sq += vv * vv;
        }
        for (int o = 32; o > 0; o >>= 1) { sum += __shfl_xor(sum, o); sq += __shfl_xor(sq, o); }
        float mu = sum * (1.f / 256.f);
        float var = sq * (1.f / 256.f) - mu * mu;
        float rstd = rsqrtf(var + 1e-5f);
#pragma unroll
        for (int k2 = 0; k2 < 4; ++k2) {
            int c = lane + 64 * k2;
            zs[r][c] = (vals[k2] - mu) * rstd * gb[c] + bb[c];
        }
    }
    __syncthreads();

    // ---- attention (32 tokens, 8 heads, no bias) ----
    int n8 = t >> 3, c08 = (t & 7) * 32;          // ownership: row n8, 32 cols
    float oacc[32];
#pragma unroll
    for (int cc = 0; cc < 32; ++cc) oacc[cc] = Bp[c08 + cc];
    for (int h = 0; h < 8; ++h) {
        for (int j = 0; j < 12; ++j) {
            int oi = j * 256 + t;
            int nn = oi / 96, c96 = oi % 96;
            int which = c96 >> 5, d = c96 & 31;
            int gcol = which * 256 + h * 32 + d;
            float acc = Bqkv[gcol];
            for (int dd = 0; dd < 256; ++dd)
                acc += zs[nn][dd] * Wqkv[(size_t)dd * 768 + gcol];
            if (which == 0) q[nn][d] = acc;
            else if (which == 1) kk[nn][d] = acc;
            else v[nn][d] = acc;
        }
        __syncthreads();
        for (int j = 0; j < 4; ++j) {
            int idx = j * 256 + t;
            int i = idx >> 5, jj = idx & 31;
            float a = 0.f;
#pragma unroll
            for (int d = 0; d < 32; ++d) a += q[i][d] * kk[jj][d];
            s[i][jj] = a * 0.17677669529663689f;
        }
        __syncthreads();
        {
            int r = t >> 3, sub = t & 7;
            float mx = -1e30f;
            for (int jj = sub; jj < 32; jj += 8) mx = fmaxf(mx, s[r][jj]);
            for (int o = 1; o < 8; o <<= 1) mx = fmaxf(mx, __shfl_xor(mx, o));
            float sum = 0.f;
            for (int jj = sub; jj < 32; jj += 8) { float e = __expf(s[r][jj] - mx); s[r][jj] = e; sum += e; }
            for (int o = 1; o < 8; o <<= 1) sum += __shfl_xor(sum, o);
            float inv = 1.f / sum;
            for (int jj = sub; jj < 32; jj += 8) s[r][jj] *= inv;
        }
        __syncthreads();
        {
            float od[32];
#pragma unroll
            for (int d = 0; d < 32; ++d) {
                float a = 0.f;
                for (int jj = 0; jj < 32; ++jj) a += s[n8][jj] * v[jj][d];
                od[d] = a;
            }
            for (int d = 0; d < 32; ++d) {
                const float* wrow = Wp + (size_t)(h * 32 + d) * 256 + c08;
                float ov = od[d];
#pragma unroll
                for (int cc = 0; cc < 32; ++cc) oacc[cc] += ov * wrow[cc];
            }
        }
        __syncthreads();
    }
    // ---- z = attention output (no residual) -> zs ----
    for (int cc = 0; cc < 32; ++cc) zs[n8][c08 + cc] = oacc[cc];
    __syncthreads();
    // ---- MLP (no residual) ----
    float oacc2[32];
#pragma unroll
    for (int cc = 0; cc < 32; ++cc) oacc2[cc] = B2[c08 + cc];
    for (int tile = 0; tile < 16; ++tile) {
        for (int j = 0; j < 8; ++j) {
            int oi = j * 256 + t;
            int nn = oi >> 6, jj = oi & 63;
            int col = tile * 64 + jj;
            float acc = B1[col];
            for (int dd = 0; dd < 256; ++dd)
                acc += zs[nn][dd] * W1[(size_t)dd * 1024 + col];
            s[nn][jj] = gelu_exact(acc);          // s reused as htile
        }
        __syncthreads();
        for (int jj = 0; jj < 64; ++jj) {
            float hv = s[n8][jj];
            const float* wrow = W2 + (size_t)(tile * 64 + jj) * 256 + c08;
#pragma unroll
            for (int cc = 0; cc < 32; ++cc) oacc2[cc] += hv * wrow[cc];
        }
        __syncthreads();
    }
    // ---- broadcast add over N (fp32 RMW) ----
    for (int nn = 0; nn < 64; ++nn) {
        size_t rowb = base + (size_t)(n8 * 64 + nn) * 256 + c08;
        for (int cc = 0; cc < 32; ++cc)
            out[rowb + cc] += oacc2[cc];
    }
}

extern "C" void kernel_launch(void* const* d_in, const int* in_sizes, int n_in,
                              void* d_out, int out_size, void* d_ws, size_t ws_size,
                              hipStream_t stream) {
    (void)in_sizes; (void)n_in; (void)out_size; (void)ws_size;
    const float* x        = (const float*)d_in[0];
    const float* mask     = (const float*)d_in[1];
    const float* adj      = (const float*)d_in[2];
    const float* dn1_g    = (const float*)d_in[3];
    const float* dn1_b    = (const float*)d_in[4];
    const float* dn2_g    = (const float*)d_in[5];
    const float* dn2_b    = (const float*)d_in[6];
    const float* bn1_g    = (const float*)d_in[7];
    const float* bn1_b    = (const float*)d_in[8];
    const float* d_qkv_w  = (const float*)d_in[9];
    const float* d_qkv_b  = (const float*)d_in[10];
    const float* d_proj_w = (const float*)d_in[11];
    const float* d_proj_b = (const float*)d_in[12];
    const float* d_fc1_w  = (const float*)d_in[13];
    const float* d_fc1_b  = (const float*)d_in[14];
    const float* d_fc2_w  = (const float*)d_in[15];
    const float* d_fc2_b  = (const float*)d_in[16];
    const float* b_qkv_w  = (const float*)d_in[17];
    const float* b_qkv_b  = (const float*)d_in[18];
    const float* b_proj_w = (const float*)d_in[19];
    const float* b_proj_b = (const float*)d_in[20];
    const float* b_fc1_w  = (const float*)d_in[21];
    const float* b_fc1_b  = (const float*)d_in[22];
    const float* b_fc2_w  = (const float*)d_in[23];
    const float* b_fc2_b  = (const float*)d_in[24];
    float* out = (float*)d_out;   // reference output dtype is float32

    // workspace: W1t (1024x256 bf16 = 512KB) + W2t (256x1024 bf16 = 512KB)
    unsigned short* W1t = (unsigned short*)d_ws;
    unsigned short* W2t = W1t + 262144;

    pack_weights_k<<<1280, 256, 0, stream>>>(d_fc1_w, d_fc2_w, W1t, W2t);
    attn_block_k<<<1024, 256, 0, stream>>>(x, mask, adj, dn1_g, dn1_b,
                                           d_qkv_w, d_qkv_b, d_proj_w, d_proj_b, out);
    mlp_mfma_k<<<1024, 256, 0, stream>>>(mask, dn2_g, dn2_b,
                                         W1t, d_fc1_b, W2t, d_fc2_b, out);
    zbranch_k<<<32, 256, 0, stream>>>(mask, bn1_g, bn1_b,
                                      b_qkv_w, b_qkv_b, b_proj_w, b_proj_b,
                                      b_fc1_w, b_fc1_b, b_fc2_w, b_fc2_b, out);
}

// Round 2
// 3766.447 us; speedup vs baseline: 4.7345x; 2.0785x over previous
//
#include <hip/hip_runtime.h>
#include <hip/hip_bf16.h>
#include <math.h>

typedef __attribute__((ext_vector_type(8))) short short8;
typedef __attribute__((ext_vector_type(4))) float floatx4;

__device__ __forceinline__ float u2f(unsigned short u) {
    union { unsigned int i; float f; } x; x.i = ((unsigned int)u) << 16; return x.f;
}
__device__ __forceinline__ unsigned short f2u(float f) {
    union { float f; unsigned int i; } c; c.f = f;
    unsigned int r = c.i + 0x7FFF + ((c.i >> 16) & 1);   // round-to-nearest-even
    return (unsigned short)(r >> 16);
}
__device__ __forceinline__ float gelu_exact(float x) {
    return 0.5f * x * (1.0f + erff(x * 0.7071067811865475f));
}

// ===================== Kernel P: pack weights to bf16, k-contiguous ========
// W1t  [1024][256] = W1^T   | W2t [256][1024] = W2^T
// Wqkvt[ 768][256] = Wqkv^T | Wpt [256][ 256] = Wp^T
__global__ __launch_bounds__(256) void pack_weights_k(
    const float* __restrict__ W1, const float* __restrict__ W2,
    const float* __restrict__ Wqkv, const float* __restrict__ Wp,
    unsigned short* __restrict__ W1t, unsigned short* __restrict__ W2t,
    unsigned short* __restrict__ Wqkvt, unsigned short* __restrict__ Wpt)
{
    int b = blockIdx.x, t = threadIdx.x;
    if (b < 1024) {
        W1t[(size_t)b * 256 + t] = f2u(W1[(size_t)t * 1024 + b]);
    } else if (b < 1280) {
        int n = b - 1024;
        for (int it = 0; it < 4; ++it) {
            int k = it * 256 + t;
            W2t[(size_t)n * 1024 + k] = f2u(W2[(size_t)k * 256 + n]);
        }
    } else if (b < 2048) {
        int c = b - 1280;
        Wqkvt[(size_t)c * 256 + t] = f2u(Wqkv[(size_t)t * 768 + c]);
    } else {
        int c = b - 2048;
        Wpt[(size_t)c * 256 + t] = f2u(Wp[(size_t)t * 256 + c]);
    }
}

// ===================== Kernel A: LN1 + window attention (MFMA) =============
// One block per window (1024 blocks, 256 threads = 4 waves).
// Per head: QKV GEMM (48 MFMA/wave, B-frags direct from global/L2),
// scores (4 MFMA), in-register softmax, PV (4 MFMA), proj accumulate (16 MFMA).
__global__ __launch_bounds__(256, 2) void attn_mfma_k(
    const float* __restrict__ x, const float* __restrict__ mask,
    const float* __restrict__ adj,
    const float* __restrict__ g1, const float* __restrict__ be1,
    const unsigned short* __restrict__ Wqkvt, const float* __restrict__ Bqkv,
    const unsigned short* __restrict__ Wpt, const float* __restrict__ Bp,
    float* __restrict__ out)
{
    __shared__ unsigned short Ybuf[64][264];   // 33792 B (stride 528B -> 2-way, free)
    __shared__ unsigned short qb[64][40];      //  5120 B
    __shared__ unsigned short kb[64][40];      //  5120 B
    __shared__ unsigned short Vt[32][72];      //  4608 B  (V transposed: Vt[d][n])
    __shared__ unsigned short Pb[64][72];      //  9216 B  (softmax probs, bf16)
    __shared__ unsigned short Ob[64][40];      //  5120 B  (per-head attn out)
    // total 62976 B -> 2 blocks/CU

    int w = blockIdx.x, p = w & 31, t = threadIdx.x;
    int wave = t >> 6, lane = t & 63;
    int l15 = lane & 15, kw = lane >> 4;
    size_t base = (size_t)w * 16384;

    // ---- LN1 over D=256 per row -> bf16 Ybuf; also out = x (residual init) ----
    for (int it = 0; it < 16; ++it) {
        int r = it * 4 + wave;
        float vals[4]; float sum = 0.f, sq = 0.f;
#pragma unroll
        for (int k2 = 0; k2 < 4; ++k2) {
            float vv = x[base + (size_t)r * 256 + lane + 64 * k2];
            vals[k2] = vv; sum += vv; sq += vv * vv;
        }
        for (int o = 32; o > 0; o >>= 1) { sum += __shfl_xor(sum, o); sq += __shfl_xor(sq, o); }
        float mu = sum * (1.f / 256.f);
        float var = sq * (1.f / 256.f) - mu * mu;
        float rstd = rsqrtf(var + 1e-5f);
#pragma unroll
        for (int k2 = 0; k2 < 4; ++k2) {
            int c = lane + 64 * k2;
            Ybuf[r][c] = f2u((vals[k2] - mu) * rstd * g1[c] + be1[c]);
            out[base + (size_t)r * 256 + c] = vals[k2];
        }
    }
    __syncthreads();

    // ---- hoist this wave's Y A-fragments (16 rows x 256 k) into registers ----
    short8 ay[8];
#pragma unroll
    for (int ks = 0; ks < 8; ++ks)
        ay[ks] = *(const short8*)(&Ybuf[wave * 16 + l15][ks * 32 + kw * 8]);

    // ---- precompute log(adj+1e-6) for this lane's score elements ----
    float ladj[4][4];   // [colfrag][reg]
#pragma unroll
    for (int cf = 0; cf < 4; ++cf)
#pragma unroll
        for (int jj = 0; jj < 4; ++jj) {
            int r = wave * 16 + kw * 4 + jj;
            int c = cf * 16 + l15;
            ladj[cf][jj] = logf(adj[r * 64 + c] + 1e-6f);
        }

    // ---- persistent proj accumulator: wave owns rows [wave*16,+16) x 256 cols ----
    floatx4 oacc[16];
#pragma unroll
    for (int cf = 0; cf < 16; ++cf) {
        float bb = Bp[cf * 16 + l15];
        oacc[cf] = (floatx4){bb, bb, bb, bb};
    }

    const float sc = 0.17677669529663689f;   // 1/sqrt(32)

    for (int h = 0; h < 8; ++h) {
        // ---- QKV GEMM: 64 x 96 (q|k|v for head h), B-frags from global ----
        floatx4 qacc[6];
#pragma unroll
        for (int cf = 0; cf < 6; ++cf) {
            int gcol = (cf >> 1) * 256 + h * 32 + (cf & 1) * 16 + l15;
            float bb = Bqkv[gcol];
            qacc[cf] = (floatx4){bb, bb, bb, bb};
        }
#pragma unroll
        for (int ks = 0; ks < 8; ++ks) {
            short8 bw[6];
#pragma unroll
            for (int cf = 0; cf < 6; ++cf) {
                int gcol = (cf >> 1) * 256 + h * 32 + (cf & 1) * 16 + l15;
                bw[cf] = *(const short8*)(Wqkvt + (size_t)gcol * 256 + ks * 32 + kw * 8);
            }
#pragma unroll
            for (int cf = 0; cf < 6; ++cf)
                qacc[cf] = __builtin_amdgcn_mfma_f32_16x16x32_bf16(ay[ks], bw[cf], qacc[cf], 0, 0, 0);
        }
        // write back q, k (row-major [n][d]) and v transposed (Vt[d][n])
#pragma unroll
        for (int cf = 0; cf < 6; ++cf)
#pragma unroll
            for (int jj = 0; jj < 4; ++jj) {
                int r = wave * 16 + kw * 4 + jj;
                int d = (cf & 1) * 16 + l15;
                unsigned short ub = f2u(qacc[cf][jj]);
                if (cf < 2) qb[r][d] = ub;
                else if (cf < 4) kb[r][d] = ub;
                else Vt[d][r] = ub;
            }
        __syncthreads();

        // ---- scores: S = Q @ K^T (wave owns rows [wave*16,+16) x 64 cols) ----
        short8 aq = *(const short8*)(&qb[wave * 16 + l15][kw * 8]);
        floatx4 sacc[4];
#pragma unroll
        for (int cf = 0; cf < 4; ++cf) {
            short8 bk = *(const short8*)(&kb[cf * 16 + l15][kw * 8]);
            sacc[cf] = __builtin_amdgcn_mfma_f32_16x16x32_bf16(aq, bk,
                        (floatx4){0.f, 0.f, 0.f, 0.f}, 0, 0, 0);
        }
        // ---- softmax fully in registers (row r's 64 cols live in one
        //      16-lane group: l15 x 4 colfrags; reduce via shfl_xor bits 0-3) ----
#pragma unroll
        for (int jj = 0; jj < 4; ++jj) {
            float s0 = sacc[0][jj] * sc + ladj[0][jj];
            float s1 = sacc[1][jj] * sc + ladj[1][jj];
            float s2 = sacc[2][jj] * sc + ladj[2][jj];
            float s3 = sacc[3][jj] * sc + ladj[3][jj];
            float mx = fmaxf(fmaxf(s0, s1), fmaxf(s2, s3));
            mx = fmaxf(mx, __shfl_xor(mx, 1));
            mx = fmaxf(mx, __shfl_xor(mx, 2));
            mx = fmaxf(mx, __shfl_xor(mx, 4));
            mx = fmaxf(mx, __shfl_xor(mx, 8));
            float e0 = __expf(s0 - mx), e1 = __expf(s1 - mx);
            float e2 = __expf(s2 - mx), e3 = __expf(s3 - mx);
            float sum = e0 + e1 + e2 + e3;
            sum += __shfl_xor(sum, 1);
            sum += __shfl_xor(sum, 2);
            sum += __shfl_xor(sum, 4);
            sum += __shfl_xor(sum, 8);
            float inv = 1.f / sum;
            int r = wave * 16 + kw * 4 + jj;
            Pb[r][0 * 16 + l15] = f2u(e0 * inv);
            Pb[r][1 * 16 + l15] = f2u(e1 * inv);
            Pb[r][2 * 16 + l15] = f2u(e2 * inv);
            Pb[r][3 * 16 + l15] = f2u(e3 * inv);
        }
        __syncthreads();

        // ---- PV: O = P @ V (wave rows x 32 cols), V via Vt B-frags ----
        floatx4 oacc2[2];
#pragma unroll
        for (int cf2 = 0; cf2 < 2; ++cf2) oacc2[cf2] = (floatx4){0.f, 0.f, 0.f, 0.f};
#pragma unroll
        for (int ks = 0; ks < 2; ++ks) {
            short8 ap = *(const short8*)(&Pb[wave * 16 + l15][ks * 32 + kw * 8]);
#pragma unroll
            for (int cf2 = 0; cf2 < 2; ++cf2) {
                short8 bv = *(const short8*)(&Vt[cf2 * 16 + l15][ks * 32 + kw * 8]);
                oacc2[cf2] = __builtin_amdgcn_mfma_f32_16x16x32_bf16(ap, bv, oacc2[cf2], 0, 0, 0);
            }
        }
#pragma unroll
        for (int cf2 = 0; cf2 < 2; ++cf2)
#pragma unroll
            for (int jj = 0; jj < 4; ++jj)
                Ob[wave * 16 + kw * 4 + jj][cf2 * 16 + l15] = f2u(oacc2[cf2][jj]);
        __syncthreads();

        // ---- proj accumulate: oacc += O_h @ Wp[h*32:(h+1)*32, :] (K=32) ----
        short8 ao = *(const short8*)(&Ob[wave * 16 + l15][kw * 8]);
#pragma unroll
        for (int cf = 0; cf < 16; ++cf) {
            short8 bw = *(const short8*)(Wpt + (size_t)(cf * 16 + l15) * 256 + h * 32 + kw * 8);
            oacc[cf] = __builtin_amdgcn_mfma_f32_16x16x32_bf16(ao, bw, oacc[cf], 0, 0, 0);
        }
        __syncthreads();   // before next head overwrites qb/kb/Vt
    }

    // ---- epilogue: out += oacc * mask[p][row]  (fp32 RMW) ----
#pragma unroll
    for (int jj = 0; jj < 4; ++jj) {
        int r = wave * 16 + kw * 4 + jj;
        float mv = mask[p * 64 + r];
#pragma unroll
        for (int cf = 0; cf < 16; ++cf) {
            size_t idx = base + (size_t)r * 256 + cf * 16 + l15;
            out[idx] += oacc[cf][jj] * mv;
        }
    }
}

// ===================== Kernel B: LN2 + MLP residual (MFMA) =================
__global__ __launch_bounds__(256) void mlp_mfma_k(
    const float* __restrict__ mask,
    const float* __restrict__ g2, const float* __restrict__ be2,
    const unsigned short* __restrict__ W1t, const float* __restrict__ B1,
    const unsigned short* __restrict__ W2t, const float* __restrict__ B2,
    float* __restrict__ out)
{
    __shared__ unsigned short Ybuf[64][264];   // 33792 B
    __shared__ unsigned short Hbuf[64][72];    //  9216 B
    __shared__ unsigned short Wbuf[10240];     // 20480 B, rows of 40 shorts
    int w = blockIdx.x, p = w & 31, t = threadIdx.x;
    int wave = t >> 6, lane = t & 63;
    int l15 = lane & 15, kw = lane >> 4;
    size_t base = (size_t)w * 16384;

    // ---- LN2 from out (= x5 after attention, fp32) -> bf16 Ybuf ----
    for (int it = 0; it < 16; ++it) {
        int r = it * 4 + wave;
        float vals[4]; float sum = 0.f, sq = 0.f;
#pragma unroll
        for (int k2 = 0; k2 < 4; ++k2) {
            float vv = out[base + (size_t)r * 256 + lane + 64 * k2];
            vals[k2] = vv; sum += vv; sq += vv * vv;
        }
        for (int o = 32; o > 0; o >>= 1) { sum += __shfl_xor(sum, o); sq += __shfl_xor(sq, o); }
        float mu = sum * (1.f / 256.f);
        float var = sq * (1.f / 256.f) - mu * mu;
        float rstd = rsqrtf(var + 1e-5f);
#pragma unroll
        for (int k2 = 0; k2 < 4; ++k2) {
            int c = lane + 64 * k2;
            Ybuf[r][c] = f2u((vals[k2] - mu) * rstd * g2[c] + be2[c]);
        }
    }
    __syncthreads();

    floatx4 oacc[4][4];
#pragma unroll
    for (int m = 0; m < 4; ++m)
#pragma unroll
        for (int j = 0; j < 4; ++j) {
            float bb = B2[wave * 64 + j * 16 + l15];
            oacc[m][j] = (floatx4){bb, bb, bb, bb};
        }

    for (int pass = 0; pass < 16; ++pass) {
        floatx4 facc[4];
#pragma unroll
        for (int j = 0; j < 4; ++j) {
            float bb = B1[pass * 64 + j * 16 + l15];
            facc[j] = (floatx4){bb, bb, bb, bb};
        }
        {
            int nr = t >> 2, c = t & 3;
            *(short8*)(Wbuf + nr * 40 + c * 8) =
                *(const short8*)(W1t + (size_t)(pass * 64 + nr) * 256 + c * 8);
        }
        __syncthreads();
        for (int ks = 0; ks < 8; ++ks) {
            if (ks + 1 < 8) {
                int nr = t >> 2, c = t & 3;
                *(short8*)(Wbuf + ((ks + 1) & 1) * 2560 + nr * 40 + c * 8) =
                    *(const short8*)(W1t + (size_t)(pass * 64 + nr) * 256 + (ks + 1) * 32 + c * 8);
            }
            int hh = (ks & 1) * 2560;
            short8 a = *(const short8*)(&Ybuf[wave * 16 + l15][ks * 32 + kw * 8]);
            short8 bf[4];
#pragma unroll
            for (int j = 0; j < 4; ++j)
                bf[j] = *(const short8*)(Wbuf + hh + (j * 16 + l15) * 40 + kw * 8);
#pragma unroll
            for (int j = 0; j < 4; ++j)
                facc[j] = __builtin_amdgcn_mfma_f32_16x16x32_bf16(a, bf[j], facc[j], 0, 0, 0);
            __syncthreads();
        }
#pragma unroll
        for (int j = 0; j < 4; ++j)
#pragma unroll
            for (int jj = 0; jj < 4; ++jj)
                Hbuf[wave * 16 + kw * 4 + jj][j * 16 + l15] = f2u(gelu_exact(facc[j][jj]));
        __syncthreads();

        for (int ks2 = 0; ks2 < 2; ++ks2) {
            for (int it = 0; it < 4; ++it) {
                int idx = it * 256 + t;
                int nr = idx >> 2, c = idx & 3;
                *(short8*)(Wbuf + nr * 40 + c * 8) =
                    *(const short8*)(W2t + (size_t)nr * 1024 + pass * 64 + ks2 * 32 + c * 8);
            }
            __syncthreads();
            short8 af[4], bf[4];
#pragma unroll
            for (int m = 0; m < 4; ++m)
                af[m] = *(const short8*)(&Hbuf[m * 16 + l15][ks2 * 32 + kw * 8]);
#pragma unroll
            for (int j = 0; j < 4; ++j)
                bf[j] = *(const short8*)(Wbuf + (wave * 64 + j * 16 + l15) * 40 + kw * 8);
#pragma unroll
            for (int m = 0; m < 4; ++m)
#pragma unroll
                for (int j = 0; j < 4; ++j)
                    oacc[m][j] = __builtin_amdgcn_mfma_f32_16x16x32_bf16(af[m], bf[j], oacc[m][j], 0, 0, 0);
            __syncthreads();
        }
    }

#pragma unroll
    for (int m = 0; m < 4; ++m) {
#pragma unroll
        for (int jj = 0; jj < 4; ++jj) {
            int r = m * 16 + kw * 4 + jj;
            float mv = mask[p * 64 + r];
#pragma unroll
            for (int j = 0; j < 4; ++j) {
                size_t idx = base + (size_t)r * 256 + wave * 64 + j * 16 + l15;
                out[idx] += oacc[m][j][jj] * mv;
            }
        }
    }
}

// ===================== Kernel C: pooled z-branch ============================
__global__ __launch_bounds__(256) void zbranch_k(
    const float* __restrict__ mask,
    const float* __restrict__ gb, const float* __restrict__ bb,
    const float* __restrict__ Wqkv, const float* __restrict__ Bqkv,
    const float* __restrict__ Wp, const float* __restrict__ Bp,
    const float* __restrict__ W1, const float* __restrict__ B1,
    const float* __restrict__ W2, const float* __restrict__ B2,
    float* __restrict__ out)
{
    __shared__ float zs[32][257];
    __shared__ float q[32][33], kk[32][33], v[32][33];
    __shared__ float s[32][65];
    int bt = blockIdx.x, t = threadIdx.x;
    int wave = t >> 6, lane = t & 63;
    size_t base = (size_t)bt * 524288;

    for (int j = 0; j < 32; ++j) {
        int oi = j * 256 + t;
        int p = oi >> 8, c = oi & 255;
        float msum = 0.f, acc = 0.f;
        for (int nn = 0; nn < 64; ++nn) {
            float mv = mask[p * 64 + nn];
            msum += mv;
            acc += mv * out[base + (size_t)(p * 64 + nn) * 256 + c];
        }
        zs[p][c] = acc / fmaxf(msum, 1.0f);
    }
    __syncthreads();
    for (int it = 0; it < 8; ++it) {
        int r = it * 4 + wave;
        float vals[4]; float sum = 0.f, sq = 0.f;
#pragma unroll
        for (int k2 = 0; k2 < 4; ++k2) {
            float vv = zs[r][lane + 64 * k2];
            vals[k2] = vv; sum += vv; sq += vv * vv;
        }
        for (int o = 32; o > 0; o >>= 1) { sum += __shfl_xor(sum, o); sq += __shfl_xor(sq, o); }
        float mu = sum * (1.f / 256.f);
        float var = sq * (1.f / 256.f) - mu * mu;
        float rstd = rsqrtf(var + 1e-5f);
#pragma unroll
        for (int k2 = 0; k2 < 4; ++k2) {
            int c = lane + 64 * k2;
            zs[r][c] = (vals[k2] - mu) * rstd * gb[c] + bb[c];
        }
    }
    __syncthreads();

    int n8 = t >> 3, c08 = (t & 7) * 32;
    float oacc[32];
#pragma unroll
    for (int cc = 0; cc < 32; ++cc) oacc[cc] = Bp[c08 + cc];
    for (int h = 0; h < 8; ++h) {
        for (int j = 0; j < 12; ++j) {
            int oi = j * 256 + t;
            int nn = oi / 96, c96 = oi % 96;
            int which = c96 >> 5, d = c96 & 31;
            int gcol = which * 256 + h * 32 + d;
            float acc = Bqkv[gcol];
            for (int dd = 0; dd < 256; ++dd)
                acc += zs[nn][dd] * Wqkv[(size_t)dd * 768 + gcol];
            if (which == 0) q[nn][d] = acc;
            else if (which == 1) kk[nn][d] = acc;
            else v[nn][d] = acc;
        }
        __syncthreads();
        for (int j = 0; j < 4; ++j) {
            int idx = j * 256 + t;
            int i = idx >> 5, jj = idx & 31;
            float a = 0.f;
#pragma unroll
            for (int d = 0; d < 32; ++d) a += q[i][d] * kk[jj][d];
            s[i][jj] = a * 0.17677669529663689f;
        }
        __syncthreads();
        {
            int r = t >> 3, sub = t & 7;
            float mx = -1e30f;
            for (int jj = sub; jj < 32; jj += 8) mx = fmaxf(mx, s[r][jj]);
            for (int o = 1; o < 8; o <<= 1) mx = fmaxf(mx, __shfl_xor(mx, o));
            float sum = 0.f;
            for (int jj = sub; jj < 32; jj += 8) { float e = __expf(s[r][jj] - mx); s[r][jj] = e; sum += e; }
            for (int o = 1; o < 8; o <<= 1) sum += __shfl_xor(sum, o);
            float inv = 1.f / sum;
            for (int jj = sub; jj < 32; jj += 8) s[r][jj] *= inv;
        }
        __syncthreads();
        {
            float od[32];
#pragma unroll
            for (int d = 0; d < 32; ++d) {
                float a = 0.f;
                for (int jj = 0; jj < 32; ++jj) a += s[n8][jj] * v[jj][d];
                od[d] = a;
            }
            for (int d = 0; d < 32; ++d) {
                const float* wrow = Wp + (size_t)(h * 32 + d) * 256 + c08;
                float ov = od[d];
#pragma unroll
                for (int cc = 0; cc < 32; ++cc) oacc[cc] += ov * wrow[cc];
            }
        }
        __syncthreads();
    }
    for (int cc = 0; cc < 32; ++cc) zs[n8][c08 + cc] = oacc[cc];
    __syncthreads();
    float oacc2[32];
#pragma unroll
    for (int cc = 0; cc < 32; ++cc) oacc2[cc] = B2[c08 + cc];
    for (int tile = 0; tile < 16; ++tile) {
        for (int j = 0; j < 8; ++j) {
            int oi = j * 256 + t;
            int nn = oi >> 6, jj = oi & 63;
            int col = tile * 64 + jj;
            float acc = B1[col];
            for (int dd = 0; dd < 256; ++dd)
                acc += zs[nn][dd] * W1[(size_t)dd * 1024 + col];
            s[nn][jj] = gelu_exact(acc);
        }
        __syncthreads();
        for (int jj = 0; jj < 64; ++jj) {
            float hv = s[n8][jj];
            const float* wrow = W2 + (size_t)(tile * 64 + jj) * 256 + c08;
#pragma unroll
            for (int cc = 0; cc < 32; ++cc) oacc2[cc] += hv * wrow[cc];
        }
        __syncthreads();
    }
    for (int nn = 0; nn < 64; ++nn) {
        size_t rowb = base + (size_t)(n8 * 64 + nn) * 256 + c08;
        for (int cc = 0; cc < 32; ++cc)
            out[rowb + cc] += oacc2[cc];
    }
}

extern "C" void kernel_launch(void* const* d_in, const int* in_sizes, int n_in,
                              void* d_out, int out_size, void* d_ws, size_t ws_size,
                              hipStream_t stream) {
    (void)in_sizes; (void)n_in; (void)out_size; (void)ws_size;
    const float* x        = (const float*)d_in[0];
    const float* mask     = (const float*)d_in[1];
    const float* adj      = (const float*)d_in[2];
    const float* dn1_g    = (const float*)d_in[3];
    const float* dn1_b    = (const float*)d_in[4];
    const float* dn2_g    = (const float*)d_in[5];
    const float* dn2_b    = (const float*)d_in[6];
    const float* bn1_g    = (const float*)d_in[7];
    const float* bn1_b    = (const float*)d_in[8];
    const float* d_qkv_w  = (const float*)d_in[9];
    const float* d_qkv_b  = (const float*)d_in[10];
    const float* d_proj_w = (const float*)d_in[11];
    const float* d_proj_b = (const float*)d_in[12];
    const float* d_fc1_w  = (const float*)d_in[13];
    const float* d_fc1_b  = (const float*)d_in[14];
    const float* d_fc2_w  = (const float*)d_in[15];
    const float* d_fc2_b  = (const float*)d_in[16];
    const float* b_qkv_w  = (const float*)d_in[17];
    const float* b_qkv_b  = (const float*)d_in[18];
    const float* b_proj_w = (const float*)d_in[19];
    const float* b_proj_b = (const float*)d_in[20];
    const float* b_fc1_w  = (const float*)d_in[21];
    const float* b_fc1_b  = (const float*)d_in[22];
    const float* b_fc2_w  = (const float*)d_in[23];
    const float* b_fc2_b  = (const float*)d_in[24];
    float* out = (float*)d_out;

    // workspace: W1t 512KB | W2t 512KB | Wqkvt 384KB | Wpt 128KB  (bf16)
    unsigned short* W1t   = (unsigned short*)d_ws;
    unsigned short* W2t   = W1t + 262144;
    unsigned short* Wqkvt = W2t + 262144;
    unsigned short* Wpt   = Wqkvt + 196608;

    pack_weights_k<<<2304, 256, 0, stream>>>(d_fc1_w, d_fc2_w, d_qkv_w, d_proj_w,
                                             W1t, W2t, Wqkvt, Wpt);
    attn_mfma_k<<<1024, 256, 0, stream>>>(x, mask, adj, dn1_g, dn1_b,
                                          Wqkvt, d_qkv_b, Wpt, d_proj_b, out);
    mlp_mfma_k<<<1024, 256, 0, stream>>>(mask, dn2_g, dn2_b,
                                         W1t, d_fc1_b, W2t, d_fc2_b, out);
    zbranch_k<<<32, 256, 0, stream>>>(mask, bn1_g, bn1_b,
                                      b_qkv_w, b_qkv_b, b_proj_w, b_proj_b,
                                      b_fc1_w, b_fc1_b, b_fc2_w, b_fc2_b, out);
}

// Round 3
// 840.268 us; speedup vs baseline: 21.2219x; 4.4824x over previous
//
#include <hip/hip_runtime.h>
#include <hip/hip_bf16.h>
#include <math.h>

typedef __attribute__((ext_vector_type(8))) short short8;
typedef __attribute__((ext_vector_type(4))) float floatx4;

__device__ __forceinline__ float u2f(unsigned short u) {
    union { unsigned int i; float f; } x; x.i = ((unsigned int)u) << 16; return x.f;
}
__device__ __forceinline__ unsigned short f2u(float f) {
    union { float f; unsigned int i; } c; c.f = f;
    unsigned int r = c.i + 0x7FFF + ((c.i >> 16) & 1);   // round-to-nearest-even
    return (unsigned short)(r >> 16);
}
__device__ __forceinline__ float gelu_exact(float x) {
    return 0.5f * x * (1.0f + erff(x * 0.7071067811865475f));
}

// ===================== Kernel P: pack all weights to bf16, k-contiguous =====
// d-branch: W1t[1024][256], W2t[256][1024], Wqkvt[768][256], Wpt[256][256]
// b-branch: bW1t[1024][256], bW2t[256][1024], bWqkvt[768][256], bWpt[256][256]
__global__ __launch_bounds__(256) void pack_weights_k(
    const float* __restrict__ W1, const float* __restrict__ W2,
    const float* __restrict__ Wqkv, const float* __restrict__ Wp,
    const float* __restrict__ bW1, const float* __restrict__ bW2,
    const float* __restrict__ bWqkv, const float* __restrict__ bWp,
    unsigned short* __restrict__ W1t, unsigned short* __restrict__ W2t,
    unsigned short* __restrict__ Wqkvt, unsigned short* __restrict__ Wpt,
    unsigned short* __restrict__ bW1t, unsigned short* __restrict__ bW2t,
    unsigned short* __restrict__ bWqkvt, unsigned short* __restrict__ bWpt)
{
    int b = blockIdx.x, t = threadIdx.x;
    if (b < 1024) {
        W1t[(size_t)b * 256 + t] = f2u(W1[(size_t)t * 1024 + b]);
    } else if (b < 1280) {
        int n = b - 1024;
        for (int it = 0; it < 4; ++it) {
            int k = it * 256 + t;
            W2t[(size_t)n * 1024 + k] = f2u(W2[(size_t)k * 256 + n]);
        }
    } else if (b < 2048) {
        int c = b - 1280;
        Wqkvt[(size_t)c * 256 + t] = f2u(Wqkv[(size_t)t * 768 + c]);
    } else if (b < 2304) {
        int c = b - 2048;
        Wpt[(size_t)c * 256 + t] = f2u(Wp[(size_t)t * 256 + c]);
    } else if (b < 3328) {
        int c = b - 2304;
        bW1t[(size_t)c * 256 + t] = f2u(bW1[(size_t)t * 1024 + c]);
    } else if (b < 3584) {
        int n = b - 3328;
        for (int it = 0; it < 4; ++it) {
            int k = it * 256 + t;
            bW2t[(size_t)n * 1024 + k] = f2u(bW2[(size_t)k * 256 + n]);
        }
    } else if (b < 4352) {
        int c = b - 3584;
        bWqkvt[(size_t)c * 256 + t] = f2u(bWqkv[(size_t)t * 768 + c]);
    } else {
        int c = b - 4352;
        bWpt[(size_t)c * 256 + t] = f2u(bWp[(size_t)t * 256 + c]);
    }
}

// ===================== Kernel A: LN1 + window attention (MFMA) =============
__global__ __launch_bounds__(256, 2) void attn_mfma_k(
    const float* __restrict__ x, const float* __restrict__ mask,
    const float* __restrict__ adj,
    const float* __restrict__ g1, const float* __restrict__ be1,
    const unsigned short* __restrict__ Wqkvt, const float* __restrict__ Bqkv,
    const unsigned short* __restrict__ Wpt, const float* __restrict__ Bp,
    float* __restrict__ out)
{
    __shared__ unsigned short Ybuf[64][264];
    __shared__ unsigned short qb[64][40];
    __shared__ unsigned short kb[64][40];
    __shared__ unsigned short Vt[32][72];
    __shared__ unsigned short Pb[64][72];
    __shared__ unsigned short Ob[64][40];

    int w = blockIdx.x, p = w & 31, t = threadIdx.x;
    int wave = t >> 6, lane = t & 63;
    int l15 = lane & 15, kw = lane >> 4;
    size_t base = (size_t)w * 16384;

    for (int it = 0; it < 16; ++it) {
        int r = it * 4 + wave;
        float vals[4]; float sum = 0.f, sq = 0.f;
#pragma unroll
        for (int k2 = 0; k2 < 4; ++k2) {
            float vv = x[base + (size_t)r * 256 + lane + 64 * k2];
            vals[k2] = vv; sum += vv; sq += vv * vv;
        }
        for (int o = 32; o > 0; o >>= 1) { sum += __shfl_xor(sum, o); sq += __shfl_xor(sq, o); }
        float mu = sum * (1.f / 256.f);
        float var = sq * (1.f / 256.f) - mu * mu;
        float rstd = rsqrtf(var + 1e-5f);
#pragma unroll
        for (int k2 = 0; k2 < 4; ++k2) {
            int c = lane + 64 * k2;
            Ybuf[r][c] = f2u((vals[k2] - mu) * rstd * g1[c] + be1[c]);
            out[base + (size_t)r * 256 + c] = vals[k2];
        }
    }
    __syncthreads();

    short8 ay[8];
#pragma unroll
    for (int ks = 0; ks < 8; ++ks)
        ay[ks] = *(const short8*)(&Ybuf[wave * 16 + l15][ks * 32 + kw * 8]);

    float ladj[4][4];
#pragma unroll
    for (int cf = 0; cf < 4; ++cf)
#pragma unroll
        for (int jj = 0; jj < 4; ++jj) {
            int r = wave * 16 + kw * 4 + jj;
            int c = cf * 16 + l15;
            ladj[cf][jj] = logf(adj[r * 64 + c] + 1e-6f);
        }

    floatx4 oacc[16];
#pragma unroll
    for (int cf = 0; cf < 16; ++cf) {
        float bb = Bp[cf * 16 + l15];
        oacc[cf] = (floatx4){bb, bb, bb, bb};
    }

    const float sc = 0.17677669529663689f;

    for (int h = 0; h < 8; ++h) {
        floatx4 qacc[6];
#pragma unroll
        for (int cf = 0; cf < 6; ++cf) {
            int gcol = (cf >> 1) * 256 + h * 32 + (cf & 1) * 16 + l15;
            float bb = Bqkv[gcol];
            qacc[cf] = (floatx4){bb, bb, bb, bb};
        }
#pragma unroll
        for (int ks = 0; ks < 8; ++ks) {
            short8 bw[6];
#pragma unroll
            for (int cf = 0; cf < 6; ++cf) {
                int gcol = (cf >> 1) * 256 + h * 32 + (cf & 1) * 16 + l15;
                bw[cf] = *(const short8*)(Wqkvt + (size_t)gcol * 256 + ks * 32 + kw * 8);
            }
#pragma unroll
            for (int cf = 0; cf < 6; ++cf)
                qacc[cf] = __builtin_amdgcn_mfma_f32_16x16x32_bf16(ay[ks], bw[cf], qacc[cf], 0, 0, 0);
        }
#pragma unroll
        for (int cf = 0; cf < 6; ++cf)
#pragma unroll
            for (int jj = 0; jj < 4; ++jj) {
                int r = wave * 16 + kw * 4 + jj;
                int d = (cf & 1) * 16 + l15;
                unsigned short ub = f2u(qacc[cf][jj]);
                if (cf < 2) qb[r][d] = ub;
                else if (cf < 4) kb[r][d] = ub;
                else Vt[d][r] = ub;
            }
        __syncthreads();

        short8 aq = *(const short8*)(&qb[wave * 16 + l15][kw * 8]);
        floatx4 sacc[4];
#pragma unroll
        for (int cf = 0; cf < 4; ++cf) {
            short8 bk = *(const short8*)(&kb[cf * 16 + l15][kw * 8]);
            sacc[cf] = __builtin_amdgcn_mfma_f32_16x16x32_bf16(aq, bk,
                        (floatx4){0.f, 0.f, 0.f, 0.f}, 0, 0, 0);
        }
#pragma unroll
        for (int jj = 0; jj < 4; ++jj) {
            float s0 = sacc[0][jj] * sc + ladj[0][jj];
            float s1 = sacc[1][jj] * sc + ladj[1][jj];
            float s2 = sacc[2][jj] * sc + ladj[2][jj];
            float s3 = sacc[3][jj] * sc + ladj[3][jj];
            float mx = fmaxf(fmaxf(s0, s1), fmaxf(s2, s3));
            mx = fmaxf(mx, __shfl_xor(mx, 1));
            mx = fmaxf(mx, __shfl_xor(mx, 2));
            mx = fmaxf(mx, __shfl_xor(mx, 4));
            mx = fmaxf(mx, __shfl_xor(mx, 8));
            float e0 = __expf(s0 - mx), e1 = __expf(s1 - mx);
            float e2 = __expf(s2 - mx), e3 = __expf(s3 - mx);
            float sum = e0 + e1 + e2 + e3;
            sum += __shfl_xor(sum, 1);
            sum += __shfl_xor(sum, 2);
            sum += __shfl_xor(sum, 4);
            sum += __shfl_xor(sum, 8);
            float inv = 1.f / sum;
            int r = wave * 16 + kw * 4 + jj;
            Pb[r][0 * 16 + l15] = f2u(e0 * inv);
            Pb[r][1 * 16 + l15] = f2u(e1 * inv);
            Pb[r][2 * 16 + l15] = f2u(e2 * inv);
            Pb[r][3 * 16 + l15] = f2u(e3 * inv);
        }
        __syncthreads();

        floatx4 oacc2[2];
#pragma unroll
        for (int cf2 = 0; cf2 < 2; ++cf2) oacc2[cf2] = (floatx4){0.f, 0.f, 0.f, 0.f};
#pragma unroll
        for (int ks = 0; ks < 2; ++ks) {
            short8 ap = *(const short8*)(&Pb[wave * 16 + l15][ks * 32 + kw * 8]);
#pragma unroll
            for (int cf2 = 0; cf2 < 2; ++cf2) {
                short8 bv = *(const short8*)(&Vt[cf2 * 16 + l15][ks * 32 + kw * 8]);
                oacc2[cf2] = __builtin_amdgcn_mfma_f32_16x16x32_bf16(ap, bv, oacc2[cf2], 0, 0, 0);
            }
        }
#pragma unroll
        for (int cf2 = 0; cf2 < 2; ++cf2)
#pragma unroll
            for (int jj = 0; jj < 4; ++jj)
                Ob[wave * 16 + kw * 4 + jj][cf2 * 16 + l15] = f2u(oacc2[cf2][jj]);
        __syncthreads();

        short8 ao = *(const short8*)(&Ob[wave * 16 + l15][kw * 8]);
#pragma unroll
        for (int cf = 0; cf < 16; ++cf) {
            short8 bw = *(const short8*)(Wpt + (size_t)(cf * 16 + l15) * 256 + h * 32 + kw * 8);
            oacc[cf] = __builtin_amdgcn_mfma_f32_16x16x32_bf16(ao, bw, oacc[cf], 0, 0, 0);
        }
        __syncthreads();
    }

#pragma unroll
    for (int jj = 0; jj < 4; ++jj) {
        int r = wave * 16 + kw * 4 + jj;
        float mv = mask[p * 64 + r];
#pragma unroll
        for (int cf = 0; cf < 16; ++cf) {
            size_t idx = base + (size_t)r * 256 + cf * 16 + l15;
            out[idx] += oacc[cf][jj] * mv;
        }
    }
}

// ===================== Kernel B: LN2 + MLP residual (MFMA) =================
__global__ __launch_bounds__(256) void mlp_mfma_k(
    const float* __restrict__ mask,
    const float* __restrict__ g2, const float* __restrict__ be2,
    const unsigned short* __restrict__ W1t, const float* __restrict__ B1,
    const unsigned short* __restrict__ W2t, const float* __restrict__ B2,
    float* __restrict__ out)
{
    __shared__ unsigned short Ybuf[64][264];
    __shared__ unsigned short Hbuf[64][72];
    __shared__ unsigned short Wbuf[10240];
    int w = blockIdx.x, p = w & 31, t = threadIdx.x;
    int wave = t >> 6, lane = t & 63;
    int l15 = lane & 15, kw = lane >> 4;
    size_t base = (size_t)w * 16384;

    for (int it = 0; it < 16; ++it) {
        int r = it * 4 + wave;
        float vals[4]; float sum = 0.f, sq = 0.f;
#pragma unroll
        for (int k2 = 0; k2 < 4; ++k2) {
            float vv = out[base + (size_t)r * 256 + lane + 64 * k2];
            vals[k2] = vv; sum += vv; sq += vv * vv;
        }
        for (int o = 32; o > 0; o >>= 1) { sum += __shfl_xor(sum, o); sq += __shfl_xor(sq, o); }
        float mu = sum * (1.f / 256.f);
        float var = sq * (1.f / 256.f) - mu * mu;
        float rstd = rsqrtf(var + 1e-5f);
#pragma unroll
        for (int k2 = 0; k2 < 4; ++k2) {
            int c = lane + 64 * k2;
            Ybuf[r][c] = f2u((vals[k2] - mu) * rstd * g2[c] + be2[c]);
        }
    }
    __syncthreads();

    floatx4 oacc[4][4];
#pragma unroll
    for (int m = 0; m < 4; ++m)
#pragma unroll
        for (int j = 0; j < 4; ++j) {
            float bb = B2[wave * 64 + j * 16 + l15];
            oacc[m][j] = (floatx4){bb, bb, bb, bb};
        }

    for (int pass = 0; pass < 16; ++pass) {
        floatx4 facc[4];
#pragma unroll
        for (int j = 0; j < 4; ++j) {
            float bb = B1[pass * 64 + j * 16 + l15];
            facc[j] = (floatx4){bb, bb, bb, bb};
        }
        {
            int nr = t >> 2, c = t & 3;
            *(short8*)(Wbuf + nr * 40 + c * 8) =
                *(const short8*)(W1t + (size_t)(pass * 64 + nr) * 256 + c * 8);
        }
        __syncthreads();
        for (int ks = 0; ks < 8; ++ks) {
            if (ks + 1 < 8) {
                int nr = t >> 2, c = t & 3;
                *(short8*)(Wbuf + ((ks + 1) & 1) * 2560 + nr * 40 + c * 8) =
                    *(const short8*)(W1t + (size_t)(pass * 64 + nr) * 256 + (ks + 1) * 32 + c * 8);
            }
            int hh = (ks & 1) * 2560;
            short8 a = *(const short8*)(&Ybuf[wave * 16 + l15][ks * 32 + kw * 8]);
            short8 bf[4];
#pragma unroll
            for (int j = 0; j < 4; ++j)
                bf[j] = *(const short8*)(Wbuf + hh + (j * 16 + l15) * 40 + kw * 8);
#pragma unroll
            for (int j = 0; j < 4; ++j)
                facc[j] = __builtin_amdgcn_mfma_f32_16x16x32_bf16(a, bf[j], facc[j], 0, 0, 0);
            __syncthreads();
        }
#pragma unroll
        for (int j = 0; j < 4; ++j)
#pragma unroll
            for (int jj = 0; jj < 4; ++jj)
                Hbuf[wave * 16 + kw * 4 + jj][j * 16 + l15] = f2u(gelu_exact(facc[j][jj]));
        __syncthreads();

        for (int ks2 = 0; ks2 < 2; ++ks2) {
            for (int it = 0; it < 4; ++it) {
                int idx = it * 256 + t;
                int nr = idx >> 2, c = idx & 3;
                *(short8*)(Wbuf + nr * 40 + c * 8) =
                    *(const short8*)(W2t + (size_t)nr * 1024 + pass * 64 + ks2 * 32 + c * 8);
            }
            __syncthreads();
            short8 af[4], bf[4];
#pragma unroll
            for (int m = 0; m < 4; ++m)
                af[m] = *(const short8*)(&Hbuf[m * 16 + l15][ks2 * 32 + kw * 8]);
#pragma unroll
            for (int j = 0; j < 4; ++j)
                bf[j] = *(const short8*)(Wbuf + (wave * 64 + j * 16 + l15) * 40 + kw * 8);
#pragma unroll
            for (int m = 0; m < 4; ++m)
#pragma unroll
                for (int j = 0; j < 4; ++j)
                    oacc[m][j] = __builtin_amdgcn_mfma_f32_16x16x32_bf16(af[m], bf[j], oacc[m][j], 0, 0, 0);
            __syncthreads();
        }
    }

#pragma unroll
    for (int m = 0; m < 4; ++m) {
#pragma unroll
        for (int jj = 0; jj < 4; ++jj) {
            int r = m * 16 + kw * 4 + jj;
            float mv = mask[p * 64 + r];
#pragma unroll
            for (int j = 0; j < 4; ++j) {
                size_t idx = base + (size_t)r * 256 + wave * 64 + j * 16 + l15;
                out[idx] += oacc[m][j][jj] * mv;
            }
        }
    }
}

// ===================== Kernel Z1: masked mean-pool + LN -> bf16 zln =========
// One block per window (1024 blocks). zln[(bt*32+p)*256 + c].
__global__ __launch_bounds__(256) void pool_ln_k(
    const float* __restrict__ out, const float* __restrict__ mask,
    const float* __restrict__ gvec, const float* __restrict__ bvec,
    unsigned short* __restrict__ zln)
{
    __shared__ float red[2][4];
    int w = blockIdx.x, p = w & 31, t = threadIdx.x;
    int wave = t >> 6, lane = t & 63;
    size_t base = (size_t)w * 16384;
    float acc = 0.f, msum = 0.f;
    for (int nn = 0; nn < 64; ++nn) {
        float mv = mask[p * 64 + nn];
        msum += mv;
        acc += mv * out[base + (size_t)nn * 256 + t];
    }
    float z = acc / fmaxf(msum, 1.f);
    float s1 = z, s2 = z * z;
    for (int o = 32; o > 0; o >>= 1) { s1 += __shfl_xor(s1, o); s2 += __shfl_xor(s2, o); }
    if (lane == 0) { red[0][wave] = s1; red[1][wave] = s2; }
    __syncthreads();
    float t1 = red[0][0] + red[0][1] + red[0][2] + red[0][3];
    float t2 = red[1][0] + red[1][1] + red[1][2] + red[1][3];
    float mu = t1 * (1.f / 256.f);
    float var = t2 * (1.f / 256.f) - mu * mu;
    float rstd = rsqrtf(var + 1e-5f);
    zln[(size_t)w * 256 + t] = f2u((z - mu) * rstd * gvec[t] + bvec[t]);
}

// ===================== Kernel Z2: z attention + MLP (MFMA), per bt ==========
// 32 blocks x 256 threads (4 waves). rt = wave&1 (row tile), cq = wave>>1.
__global__ __launch_bounds__(256) void zcompute_k(
    const unsigned short* __restrict__ zln,
    const unsigned short* __restrict__ bWqkvt, const float* __restrict__ Bqkv,
    const unsigned short* __restrict__ bWpt, const float* __restrict__ Bp,
    const unsigned short* __restrict__ bW1t, const float* __restrict__ B1,
    const unsigned short* __restrict__ bW2t, const float* __restrict__ B2,
    float* __restrict__ zout)
{
    __shared__ unsigned short Zbuf[32][264];
    __shared__ unsigned short Z2[32][264];
    __shared__ unsigned short qb[32][40], kb[32][40], Vt[32][40], Pb[32][40], Ob[32][40];
    __shared__ unsigned short Hbuf[32][72];
    int bt = blockIdx.x, t = threadIdx.x;
    int wave = t >> 6, lane = t & 63;
    int l15 = lane & 15, kw = lane >> 4;
    int rt = wave & 1, cq = wave >> 1;

    for (int i = t; i < 32 * 256; i += 256) {
        int r = i >> 8, c = i & 255;
        Zbuf[r][c] = zln[(size_t)bt * 8192 + i];
    }
    __syncthreads();

    short8 ay[8];
#pragma unroll
    for (int ks = 0; ks < 8; ++ks)
        ay[ks] = *(const short8*)(&Zbuf[rt * 16 + l15][ks * 32 + kw * 8]);

    floatx4 pacc[8];
#pragma unroll
    for (int cf = 0; cf < 8; ++cf) {
        float bb = Bp[cq * 128 + cf * 16 + l15];
        pacc[cf] = (floatx4){bb, bb, bb, bb};
    }
    const float sc = 0.17677669529663689f;

    for (int h = 0; h < 8; ++h) {
        // ---- QKV: wave computes 16 rows x 48 cols (3 16-col tiles) ----
        floatx4 qacc[3];
#pragma unroll
        for (int cf = 0; cf < 3; ++cf) {
            int c96 = cq * 48 + cf * 16 + l15;
            int gcol = (c96 >> 5) * 256 + h * 32 + (c96 & 31);
            float bb = Bqkv[gcol];
            qacc[cf] = (floatx4){bb, bb, bb, bb};
        }
#pragma unroll
        for (int ks = 0; ks < 8; ++ks) {
#pragma unroll
            for (int cf = 0; cf < 3; ++cf) {
                int c96 = cq * 48 + cf * 16 + l15;
                int gcol = (c96 >> 5) * 256 + h * 32 + (c96 & 31);
                short8 bw = *(const short8*)(bWqkvt + (size_t)gcol * 256 + ks * 32 + kw * 8);
                qacc[cf] = __builtin_amdgcn_mfma_f32_16x16x32_bf16(ay[ks], bw, qacc[cf], 0, 0, 0);
            }
        }
#pragma unroll
        for (int cf = 0; cf < 3; ++cf) {
            int c96 = cq * 48 + cf * 16 + l15;
            int which = c96 >> 5, d = c96 & 31;
#pragma unroll
            for (int jj = 0; jj < 4; ++jj) {
                int r = rt * 16 + kw * 4 + jj;
                unsigned short ub = f2u(qacc[cf][jj]);
                if (which == 0) qb[r][d] = ub;
                else if (which == 1) kb[r][d] = ub;
                else Vt[d][r] = ub;
            }
        }
        __syncthreads();
        // ---- scores + in-register softmax (waves 0,1 cover the 2 row tiles) ----
        if (wave < 2) {
            short8 aq = *(const short8*)(&qb[wave * 16 + l15][kw * 8]);
            floatx4 sacc[2];
#pragma unroll
            for (int cf = 0; cf < 2; ++cf) {
                short8 bk = *(const short8*)(&kb[cf * 16 + l15][kw * 8]);
                sacc[cf] = __builtin_amdgcn_mfma_f32_16x16x32_bf16(aq, bk,
                            (floatx4){0.f, 0.f, 0.f, 0.f}, 0, 0, 0);
            }
#pragma unroll
            for (int jj = 0; jj < 4; ++jj) {
                float s0 = sacc[0][jj] * sc;
                float s1 = sacc[1][jj] * sc;
                float mx = fmaxf(s0, s1);
                mx = fmaxf(mx, __shfl_xor(mx, 1));
                mx = fmaxf(mx, __shfl_xor(mx, 2));
                mx = fmaxf(mx, __shfl_xor(mx, 4));
                mx = fmaxf(mx, __shfl_xor(mx, 8));
                float e0 = __expf(s0 - mx), e1 = __expf(s1 - mx);
                float sum = e0 + e1;
                sum += __shfl_xor(sum, 1);
                sum += __shfl_xor(sum, 2);
                sum += __shfl_xor(sum, 4);
                sum += __shfl_xor(sum, 8);
                float inv = 1.f / sum;
                int r = wave * 16 + kw * 4 + jj;
                Pb[r][l15] = f2u(e0 * inv);
                Pb[r][16 + l15] = f2u(e1 * inv);
            }
        }
        __syncthreads();
        // ---- PV: each wave one 16x16 tile ----
        {
            short8 ap = *(const short8*)(&Pb[rt * 16 + l15][kw * 8]);
            short8 bv = *(const short8*)(&Vt[cq * 16 + l15][kw * 8]);
            floatx4 oo = __builtin_amdgcn_mfma_f32_16x16x32_bf16(ap, bv,
                          (floatx4){0.f, 0.f, 0.f, 0.f}, 0, 0, 0);
#pragma unroll
            for (int jj = 0; jj < 4; ++jj)
                Ob[rt * 16 + kw * 4 + jj][cq * 16 + l15] = f2u(oo[jj]);
        }
        __syncthreads();
        // ---- proj accumulate (K=32 for this head) ----
        {
            short8 ao = *(const short8*)(&Ob[rt * 16 + l15][kw * 8]);
#pragma unroll
            for (int cf = 0; cf < 8; ++cf) {
                int gcol = cq * 128 + cf * 16 + l15;
                short8 bw = *(const short8*)(bWpt + (size_t)gcol * 256 + h * 32 + kw * 8);
                pacc[cf] = __builtin_amdgcn_mfma_f32_16x16x32_bf16(ao, bw, pacc[cf], 0, 0, 0);
            }
        }
        __syncthreads();
    }
    // ---- z1 = attention out (no residual) -> Z2 bf16 ----
#pragma unroll
    for (int cf = 0; cf < 8; ++cf)
#pragma unroll
        for (int jj = 0; jj < 4; ++jj)
            Z2[rt * 16 + kw * 4 + jj][cq * 128 + cf * 16 + l15] = f2u(pacc[cf][jj]);
    __syncthreads();

    short8 az[8];
#pragma unroll
    for (int ks = 0; ks < 8; ++ks)
        az[ks] = *(const short8*)(&Z2[rt * 16 + l15][ks * 32 + kw * 8]);

    floatx4 oacc2[8];
#pragma unroll
    for (int cf = 0; cf < 8; ++cf) {
        float bb = B2[cq * 128 + cf * 16 + l15];
        oacc2[cf] = (floatx4){bb, bb, bb, bb};
    }
    for (int pass = 0; pass < 16; ++pass) {
        // ---- fc1: wave rows rt, cols cq*32.. (2 tiles) ----
        floatx4 facc[2];
#pragma unroll
        for (int cf = 0; cf < 2; ++cf) {
            int col = pass * 64 + cq * 32 + cf * 16 + l15;
            float bb = B1[col];
            facc[cf] = (floatx4){bb, bb, bb, bb};
        }
#pragma unroll
        for (int ks = 0; ks < 8; ++ks) {
#pragma unroll
            for (int cf = 0; cf < 2; ++cf) {
                int col = pass * 64 + cq * 32 + cf * 16 + l15;
                short8 bw = *(const short8*)(bW1t + (size_t)col * 256 + ks * 32 + kw * 8);
                facc[cf] = __builtin_amdgcn_mfma_f32_16x16x32_bf16(az[ks], bw, facc[cf], 0, 0, 0);
            }
        }
#pragma unroll
        for (int cf = 0; cf < 2; ++cf)
#pragma unroll
            for (int jj = 0; jj < 4; ++jj)
                Hbuf[rt * 16 + kw * 4 + jj][cq * 32 + cf * 16 + l15] = f2u(gelu_exact(facc[cf][jj]));
        __syncthreads();
        // ---- fc2 partial (K=64) ----
#pragma unroll
        for (int ks = 0; ks < 2; ++ks) {
            short8 ah = *(const short8*)(&Hbuf[rt * 16 + l15][ks * 32 + kw * 8]);
#pragma unroll
            for (int cf = 0; cf < 8; ++cf) {
                int gcol = cq * 128 + cf * 16 + l15;
                short8 bw = *(const short8*)(bW2t + (size_t)gcol * 1024 + pass * 64 + ks * 32 + kw * 8);
                oacc2[cf] = __builtin_amdgcn_mfma_f32_16x16x32_bf16(ah, bw, oacc2[cf], 0, 0, 0);
            }
        }
        __syncthreads();
    }
#pragma unroll
    for (int cf = 0; cf < 8; ++cf)
#pragma unroll
        for (int jj = 0; jj < 4; ++jj) {
            int r = rt * 16 + kw * 4 + jj;
            int c = cq * 128 + cf * 16 + l15;
            zout[(size_t)bt * 8192 + r * 256 + c] = oacc2[cf][jj];
        }
}

// ===================== Kernel Z3: broadcast add over N ======================
__global__ __launch_bounds__(256) void zadd_k(
    const float* __restrict__ zout, float* __restrict__ out)
{
    int w = blockIdx.x, t = threadIdx.x;
    size_t base = (size_t)w * 16384;
    float zv = zout[(size_t)w * 256 + t];
    for (int nn = 0; nn < 64; ++nn)
        out[base + (size_t)nn * 256 + t] += zv;
}

extern "C" void kernel_launch(void* const* d_in, const int* in_sizes, int n_in,
                              void* d_out, int out_size, void* d_ws, size_t ws_size,
                              hipStream_t stream) {
    (void)in_sizes; (void)n_in; (void)out_size; (void)ws_size;
    const float* x        = (const float*)d_in[0];
    const float* mask     = (const float*)d_in[1];
    const float* adj      = (const float*)d_in[2];
    const float* dn1_g    = (const float*)d_in[3];
    const float* dn1_b    = (const float*)d_in[4];
    const float* dn2_g    = (const float*)d_in[5];
    const float* dn2_b    = (const float*)d_in[6];
    const float* bn1_g    = (const float*)d_in[7];
    const float* bn1_b    = (const float*)d_in[8];
    const float* d_qkv_w  = (const float*)d_in[9];
    const float* d_qkv_b  = (const float*)d_in[10];
    const float* d_proj_w = (const float*)d_in[11];
    const float* d_proj_b = (const float*)d_in[12];
    const float* d_fc1_w  = (const float*)d_in[13];
    const float* d_fc1_b  = (const float*)d_in[14];
    const float* d_fc2_w  = (const float*)d_in[15];
    const float* d_fc2_b  = (const float*)d_in[16];
    const float* b_qkv_w  = (const float*)d_in[17];
    const float* b_qkv_b  = (const float*)d_in[18];
    const float* b_proj_w = (const float*)d_in[19];
    const float* b_proj_b = (const float*)d_in[20];
    const float* b_fc1_w  = (const float*)d_in[21];
    const float* b_fc1_b  = (const float*)d_in[22];
    const float* b_fc2_w  = (const float*)d_in[23];
    const float* b_fc2_b  = (const float*)d_in[24];
    float* out = (float*)d_out;

    // workspace layout (bf16 unless noted):
    // W1t 262144 | W2t 262144 | Wqkvt 196608 | Wpt 65536
    // bW1t 262144 | bW2t 262144 | bWqkvt 196608 | bWpt 65536
    // zln 262144 | zout fp32 262144    (total ~4.5 MB)
    unsigned short* W1t    = (unsigned short*)d_ws;
    unsigned short* W2t    = W1t + 262144;
    unsigned short* Wqkvt  = W2t + 262144;
    unsigned short* Wpt    = Wqkvt + 196608;
    unsigned short* bW1t   = Wpt + 65536;
    unsigned short* bW2t   = bW1t + 262144;
    unsigned short* bWqkvt = bW2t + 262144;
    unsigned short* bWpt   = bWqkvt + 196608;
    unsigned short* zln    = bWpt + 65536;
    float* zout            = (float*)(zln + 262144);

    pack_weights_k<<<4608, 256, 0, stream>>>(d_fc1_w, d_fc2_w, d_qkv_w, d_proj_w,
                                             b_fc1_w, b_fc2_w, b_qkv_w, b_proj_w,
                                             W1t, W2t, Wqkvt, Wpt,
                                             bW1t, bW2t, bWqkvt, bWpt);
    attn_mfma_k<<<1024, 256, 0, stream>>>(x, mask, adj, dn1_g, dn1_b,
                                          Wqkvt, d_qkv_b, Wpt, d_proj_b, out);
    mlp_mfma_k<<<1024, 256, 0, stream>>>(mask, dn2_g, dn2_b,
                                         W1t, d_fc1_b, W2t, d_fc2_b, out);
    pool_ln_k<<<1024, 256, 0, stream>>>(out, mask, bn1_g, bn1_b, zln);
    zcompute_k<<<32, 256, 0, stream>>>(zln,
                                       bWqkvt, b_qkv_b, bWpt, b_proj_b,
                                       bW1t, b_fc1_b, bW2t, b_fc2_b, zout);
    zadd_k<<<1024, 256, 0, stream>>>(zout, out);
}